// Round 7
// baseline (84.550 us; speedup 1.0000x reference)
//
#include <hip/hip_runtime.h>

// Chamfer distance, B=16, N=M=4096, 2-D fp32 points, prefix-length masks.
// d_out: [fwd 16*4096][bwd 16*4096] fp32.
//
// R7: R6 accounting (calibrated vs R1/R4 measured mains) puts main ~22-25us,
// ~2.5x the VALU model. Loop rework:
//  - LDS record 24 -> 16 B/pair: drop |t|^2 plane, recompute n = x^2+y^2 per
//    j with 2 packed instrs amortized over 16 queries. LDS util 75% -> 48%.
//  - Masking via poisoned COORDS (x=1e15 -> d2 ~ 1e30 always loses; every
//    active chunk has >=1 valid point, so real min < 1e10 survives).
//  - __builtin_elementwise_fma on float2 ext-vectors with splatted
//    multiplicands: guaranteed v_pk_fma_f32 (no op_sel pattern-match gamble).
// Keep: compacted dispatch (g -> g-th active (row, 128-pt chunk)), zero
// atomics/fences (R3 lesson), plain partial stores + kernel-boundary
// visibility, reduce over nact slices + sqrt + mask.

#define NQ 16
typedef float f2 __attribute__((ext_vector_type(2)));

__global__ __launch_bounds__(256, 2) void chamfer_main(
    const float* __restrict__ src, const float* __restrict__ tgt,
    const int* __restrict__ slen, const int* __restrict__ tlen,
    float* __restrict__ part)   // [32 rows][32 slices][4096] partial mins
{
    __shared__ float4 sh_xy[64];   // {x0,x1,y0,y1} per point-pair (16 B/pair)

    const int g   = blockIdx.x;
    const int tid = threadIdx.x;

    // Compacted work lookup: g -> (row, pc). Uniform SALU.
    int row = -1, pc = 0, Lp = 0, acc = 0;
    #pragma unroll
    for (int rr = 0; rr < 32; ++rr) {
        const int L = (rr < 16) ? tlen[rr] : slen[rr - 16];  // search-side length
        const int n = (L + 127) >> 7;                        // active 128-pt chunks
        if (row < 0 && g < acc + n) { row = rr; pc = g - acc; Lp = L; }
        acc += n;
    }
    if (row < 0) return;             // beyond total active units
    const int dir = row >> 4, b = row & 15;

    const float* Q = dir ? tgt : src;
    const float* P = dir ? src : tgt;

    // Stage 128 points (64 pairs), pair-packed; POISON COORDS for idx >= Lp
    // (1e15^2 = 1e30 dominates any real d2; chunk has >=1 valid point).
    if (tid < 64) {
        const int base = pc * 128 + tid * 2;
        const float4 pp = ((const float4*)P)[(b * 4096 + base) >> 1];  // {x0,y0,x1,y1}
        const float x0 = (base + 0 < Lp) ? pp.x : 1e15f;
        const float y0 = (base + 0 < Lp) ? pp.y : 1e15f;
        const float x1 = (base + 1 < Lp) ? pp.z : 1e15f;
        const float y1 = (base + 1 < Lp) ? pp.w : 1e15f;
        sh_xy[tid] = make_float4(x0, x1, y0, y1);            // {x0,x1,y0,y1}
    }
    __syncthreads();

    // 16 queries/thread (whole 4096-query row). Splatted -2q for packed fma.
    f2 mx2[NQ], my2[NQ];
    float s2[NQ], best[NQ];
    #pragma unroll
    for (int k = 0; k < NQ; ++k) {
        const float2 q = ((const float2*)Q)[b * 4096 + tid + k * 256];
        const float mx = -2.f * q.x, my = -2.f * q.y;
        mx2[k] = f2{mx, mx};
        my2[k] = f2{my, my};
        s2[k]  = fmaf(q.x, q.x, q.y * q.y);
        best[k] = 3.0e38f;
    }

    // Per point-pair per query: 2 v_pk_fma_f32 + 1 v_min3_f32 (1.5/pair).
    // Per j: 1 ds_read_b128 + 2 packed instrs to rebuild n = x^2+y^2.
    #pragma unroll 4
    for (int j = 0; j < 64; ++j) {
        const float4 xy = sh_xy[j];
        const f2 xp = f2{xy.x, xy.y};
        const f2 yp = f2{xy.z, xy.w};
        const f2 np = __builtin_elementwise_fma(xp, xp, yp * yp);  // pk_mul + pk_fma
        #pragma unroll
        for (int k = 0; k < NQ; ++k) {
            f2 v = __builtin_elementwise_fma(xp, mx2[k], np);  // n - 2qx*tx
            v = __builtin_elementwise_fma(yp, my2[k], v);      // n - 2q.t
            best[k] = fminf(best[k], fminf(v.x, v.y));         // v_min3_f32
        }
    }

    // Plain coalesced stores to this unit's private slice. No atomics.
    float* slice = part + ((size_t)row * 32 + pc) * 4096;
    #pragma unroll
    for (int k = 0; k < NQ; ++k)
        slice[tid + k * 256] = fmaxf(best[k] + s2[k], 0.f);  // clamp commutes with min
}

__global__ __launch_bounds__(128) void chamfer_reduce(
    const float* __restrict__ part,
    const int* __restrict__ slen, const int* __restrict__ tlen,
    float* __restrict__ out)
{
    const int t  = blockIdx.x * 128 + threadIdx.x;   // 32768 threads, 4 elems each
    const int i4 = t * 4;
    const int row = i4 >> 12;                        // dir*16 + b
    const int dir = row >> 4, b = row & 15;
    const int i   = i4 & 4095;
    const int Lq = dir ? tlen[b] : slen[b];
    const int Lp = dir ? slen[b] : tlen[b];
    const int nact = (Lp + 127) >> 7;                // active slices (block-uniform)

    float4 best = make_float4(1e10f, 1e10f, 1e10f, 1e10f);
    const float4* p = (const float4*)(part + (size_t)row * 32 * 4096 + i);
    #pragma unroll 4
    for (int s = 0; s < nact; ++s) {
        const float4 v = p[(size_t)s * 1024];        // stride 4096 floats
        best.x = fminf(best.x, v.x);
        best.y = fminf(best.y, v.y);
        best.z = fminf(best.z, v.z);
        best.w = fminf(best.w, v.w);
    }
    float4 r;
    r.x = (i + 0 < Lq) ? sqrtf(best.x) : 0.f;        // nact==0 -> sqrt(1e10), matches ref
    r.y = (i + 1 < Lq) ? sqrtf(best.y) : 0.f;
    r.z = (i + 2 < Lq) ? sqrtf(best.z) : 0.f;
    r.w = (i + 3 < Lq) ? sqrtf(best.w) : 0.f;
    ((float4*)out)[t] = r;
}

extern "C" void kernel_launch(void* const* d_in, const int* in_sizes, int n_in,
                              void* d_out, int out_size, void* d_ws, size_t ws_size,
                              hipStream_t stream) {
    const float* src = (const float*)d_in[0];   // [16,4096,2] f32
    const float* tgt = (const float*)d_in[1];   // [16,4096,2] f32
    const int* slen  = (const int*)d_in[2];     // [16] i32
    const int* tlen  = (const int*)d_in[3];     // [16] i32
    float* part = (float*)d_ws;                 // 32 x 32 x 4096 f32 = 16.8 MB

    chamfer_main<<<1024, 256, 0, stream>>>(src, tgt, slen, tlen, part);
    chamfer_reduce<<<256, 128, 0, stream>>>(part, slen, tlen, (float*)d_out);
}